// Round 7
// baseline (72.631 us; speedup 1.0000x reference)
//
#include <hip/hip_runtime.h>
#include <stdint.h>

#define R_NUM 4096
#define D_DIM 64
#define DEG_N 6
#define MF 8
#define FB_COEF 0.035355339059327376f  // FB_ALPHA * FB_SCALE = 0.1/sqrt(8)

// Native clang vector type: __builtin_nontemporal_load requires a pointer to
// scalar/vector-of-scalar, not HIP's struct float4.
typedef float f4v __attribute__((ext_vector_type(4)));

// One block per destination region r (dst = repeat(arange(R), 6) -> edges
// 6r..6r+5 all land in region r; segment-sum is a private accumulate).
//
// R7 change: issue the 6 nontemporal W loads BEFORE the wave-0 prologue and
// barrier. Their addresses depend only on blockIdx, so the memory pipe is
// fed from ~cycle 10 of every block; the barrier's vmcnt drain then overlaps
// the W flight with the prologue's mask/coords/sincos latency instead of
// serializing prologue -> stream (the R6 ordering left the HBM pipe idle for
// the whole prologue on every one of the 16 sequential blocks per CU).
__launch_bounds__(1024, 8)
__global__ void router_kernel(const float* __restrict__ H,
                              const void* __restrict__ mask_raw,
                              const float* __restrict__ coords,
                              const float* __restrict__ W_edges,
                              const float* __restrict__ W_reg,
                              const float* __restrict__ beta_cos,
                              const float* __restrict__ beta_sin,
                              const int* __restrict__ src,
                              float* __restrict__ out) {
  const int r    = blockIdx.x;
  const int t    = threadIdx.x;
  const int lane = t & 63;
  const int q    = t >> 4;          // output row 0..63
  const int j0   = (t & 15) << 2;   // starting col of this lane's float4

  __shared__ float s_w[DEG_N];
  __shared__ int   s_src[DEG_N];

  // ---- issue the 6 HBM-critical W loads immediately (nontemporal):
  // W is 403 MB touched exactly once -- evict-first keeps L2 for H/coords.
  const float* __restrict__ Wb = W_edges + (size_t)r * (DEG_N * D_DIM * D_DIM);
  const f4v wv0 = __builtin_nontemporal_load(
      reinterpret_cast<const f4v*>(Wb + 0 * (D_DIM * D_DIM) + t * 4));
  const f4v wv1 = __builtin_nontemporal_load(
      reinterpret_cast<const f4v*>(Wb + 1 * (D_DIM * D_DIM) + t * 4));
  const f4v wv2 = __builtin_nontemporal_load(
      reinterpret_cast<const f4v*>(Wb + 2 * (D_DIM * D_DIM) + t * 4));
  const f4v wv3 = __builtin_nontemporal_load(
      reinterpret_cast<const f4v*>(Wb + 3 * (D_DIM * D_DIM) + t * 4));
  const f4v wv4 = __builtin_nontemporal_load(
      reinterpret_cast<const f4v*>(Wb + 4 * (D_DIM * D_DIM) + t * 4));
  const f4v wv5 = __builtin_nontemporal_load(
      reinterpret_cast<const f4v*>(Wb + 5 * (D_DIM * D_DIM) + t * 4));

  if (t < 64) {  // wave 0 only: mask-dtype detection + edge weights
    //  flag: 0 = 1-byte bool, 1 = int32, 2 = int64, 3 = float32
    // (first 256 words = 1 KB, safe under every candidate encoding)
    const uint32_t* mw = (const uint32_t*)mask_raw;
    bool int01 = true, f01 = true, oddz = true, even1 = false;
#pragma unroll
    for (int i = 0; i < 4; ++i) {
      const int idx = lane + 64 * i;      // parity of idx == parity of lane
      const uint32_t v = mw[idx];
      int01 = int01 && (v <= 1u);
      f01   = f01 && (v == 0u || v == 0x3f800000u);
      if (lane & 1) oddz = oddz && (v == 0u);
      else          even1 = even1 || (v == 1u);
    }
    const bool all_int01 = (__ballot(int01) == ~0ULL);
    const bool all_f01   = (__ballot(f01)   == ~0ULL);
    const bool all_oddz  = (__ballot(!oddz) == 0ULL);
    const bool any_even1 = (__ballot(even1) != 0ULL);
    int mflag = 0;
    if (all_int01)    mflag = (all_oddz && any_even1) ? 2 : 1;
    else if (all_f01) mflag = 3;

    if (lane < DEG_N) {
      const int e = r * DEG_N + lane;
      const int s = src[e];
      const float dx = coords[2 * r]     - coords[2 * s];
      const float dy = coords[2 * r + 1] - coords[2 * s + 1];
      float b = 0.f;
#pragma unroll
      for (int m = 0; m < MF; ++m) {
        const float S = dx * W_reg[2 * m] + dy * W_reg[2 * m + 1];
        float sv, cv;
        __sincosf(S, &sv, &cv);
        b += cv * beta_cos[m] + sv * beta_sin[m];
      }
      bool mv;
      if (mflag == 1)      mv = ((const int*)mask_raw)[s] != 0;
      else if (mflag == 2) mv = ((const long long*)mask_raw)[s] != 0;
      else if (mflag == 3) mv = ((const float*)mask_raw)[s] != 0.f;
      else                 mv = ((const uint8_t*)mask_raw)[s] != 0;
      s_w[lane]   = mv ? fmaf(FB_COEF, b, 1.0f) : 0.f;
      s_src[lane] = s;
    }
  }
  __syncthreads();

  // ---- block-uniform edge params ----
  const int   s0 = s_src[0], s1 = s_src[1], s2 = s_src[2];
  const int   s3 = s_src[3], s4 = s_src[4], s5 = s_src[5];
  const float w0 = s_w[0], w1 = s_w[1], w2 = s_w[2];
  const float w3 = s_w[3], w4 = s_w[4], w5 = s_w[5];

  // ---- accumulate: h-gather (L1/L2-resident) x streamed W ----
  // NOTE: macro params must not collide with vector component names.
  float p = 0.f;
#define EDGE(ss, ww, vv)                                                     \
  {                                                                          \
    const float4 hv = *reinterpret_cast<const float4*>(&H[ss * D_DIM + j0]); \
    p = fmaf(ww, vv.x * hv.x + vv.y * hv.y + vv.z * hv.z + vv.w * hv.w, p);  \
  }
  EDGE(s0, w0, wv0) EDGE(s1, w1, wv1) EDGE(s2, w2, wv2)
  EDGE(s3, w3, wv3) EDGE(s4, w4, wv4) EDGE(s5, w5, wv5)
#undef EDGE

  // ---- reduce across the 16 lanes owning each row ----
#pragma unroll
  for (int off = 1; off < 16; off <<= 1) p += __shfl_xor(p, off);

  // lanes 0,16,32,48 of each wave hold rows 4w..4w+3; compact into one
  // float4 store from lane 0 of the wave.
  const float p0 = __shfl(p, 0);
  const float p1 = __shfl(p, 16);
  const float p2 = __shfl(p, 32);
  const float p3 = __shfl(p, 48);
  if (lane == 0) {
    float4 o = make_float4(p0, p1, p2, p3);
    *reinterpret_cast<float4*>(&out[r * D_DIM + (q & ~3)]) = o;
  }
}

extern "C" void kernel_launch(void* const* d_in, const int* in_sizes, int n_in,
                              void* d_out, int out_size, void* d_ws, size_t ws_size,
                              hipStream_t stream) {
  const float* H        = (const float*)d_in[0];
  const void*  mask     = d_in[1];
  const float* coords   = (const float*)d_in[2];
  const float* W_edges  = (const float*)d_in[3];
  const float* W_reg    = (const float*)d_in[4];
  const float* beta_cos = (const float*)d_in[5];
  const float* beta_sin = (const float*)d_in[6];
  const int*   src      = (const int*)d_in[7];
  // d_in[8] (dst) is structurally repeat(arange(R), 6); not needed.

  router_kernel<<<R_NUM, 1024, 0, stream>>>(H, mask, coords, W_edges, W_reg,
                                            beta_cos, beta_sin, src,
                                            (float*)d_out);
}

// Round 8
// 67.525 us; speedup vs baseline: 1.0756x; 1.0756x over previous
//
#include <hip/hip_runtime.h>
#include <stdint.h>

#define R_NUM 4096
#define D_DIM 64
#define DEG_N 6
#define MF 8
#define GRID 256                 // one persistent block per CU
#define NR (R_NUM / GRID)        // 16 regions per block
#define FB_COEF 0.035355339059327376f  // FB_ALPHA * FB_SCALE = 0.1/sqrt(8)

typedef float f4v __attribute__((ext_vector_type(4)));

// Persistent-block software pipeline (R8):
//  - grid = 256 blocks x 1024 threads, one per CU; block b owns regions
//    b, b+256, ..., b+15*256 (16 regions). Removes 15/16 of block
//    launch/teardown ramp vs the 4096-block version.
//  - All 96 edge weights (16 regions x 6 edges) are computed ONCE upfront:
//    lane l covers local edge ids {l, l+64}; later retrieval is
//    __shfl(e<64 ? wa : wb, e&63) with e compile-time static (full unroll).
//  - Steady-state loop is pure streaming: 6 H loads (L2-resident) -> 6
//    nontemporal W prefetches for region k+1 -> fma chain on region k ->
//    16-lane reduce -> one float4 store per wave. Issue order keeps the
//    H-consume wait at vmcnt(6): next-region W prefetches stay in flight.
//  - W loads nontemporal: 403 MB touched exactly once; keep L2 for H.
__launch_bounds__(1024, 4)
__global__ void router_kernel(const float* __restrict__ H,
                              const void* __restrict__ mask_raw,
                              const float* __restrict__ coords,
                              const float* __restrict__ W_edges,
                              const float* __restrict__ W_reg,
                              const float* __restrict__ beta_cos,
                              const float* __restrict__ beta_sin,
                              const int* __restrict__ src,
                              float* __restrict__ out) {
  const int r0   = blockIdx.x;
  const int t    = threadIdx.x;
  const int lane = t & 63;
  const int wid  = t >> 6;          // wave id 0..15 -> output rows 4w..4w+3
  const int j0   = (t & 15) << 2;   // starting col of this lane's float4

  // ---- per-wave mask-dtype detection over the first 256 words (1 KB;
  // safe under every candidate encoding since the bool buffer is >= 4 KB).
  //  flag: 0 = 1-byte bool, 1 = int32, 2 = int64, 3 = float32
  const uint32_t* mw = (const uint32_t*)mask_raw;
  bool int01 = true, f01 = true, oddz = true, even1 = false;
#pragma unroll
  for (int i = 0; i < 4; ++i) {
    const int idx = lane + 64 * i;        // parity of idx == parity of lane
    const uint32_t v = mw[idx];
    int01 = int01 && (v <= 1u);
    f01   = f01 && (v == 0u || v == 0x3f800000u);
    if (lane & 1) oddz = oddz && (v == 0u);
    else          even1 = even1 || (v == 1u);
  }
  const bool all_int01 = (__ballot(int01) == ~0ULL);
  const bool all_f01   = (__ballot(f01)   == ~0ULL);
  const bool all_oddz  = (__ballot(!oddz) == 0ULL);
  const bool any_even1 = (__ballot(even1) != 0ULL);
  int mflag = 0;
  if (all_int01)    mflag = (all_oddz && any_even1) ? 2 : 1;
  else if (all_f01) mflag = 3;

  // ---- upfront edge weights: local edge ids 0..95; lane covers {lane,
  // lane+64}. li -> (it = li/6, k = li%6) -> region r0+it*GRID, edge k.
  float wa = 0.f, wb = 0.f;
  int   sa = 0,   sb = 0;
#define CALC_EDGE(li, wout, sout)                                            \
  if ((li) < DEG_N * NR) {                                                   \
    const int it = (li) / DEG_N;                                             \
    const int k  = (li) % DEG_N;                                             \
    const int rr = r0 + it * GRID;                                           \
    const int e  = rr * DEG_N + k;                                           \
    const int s  = src[e];                                                   \
    sout = s;                                                                \
    const float dx = coords[2 * rr]     - coords[2 * s];                     \
    const float dy = coords[2 * rr + 1] - coords[2 * s + 1];                 \
    float b = 0.f;                                                           \
    _Pragma("unroll") for (int m = 0; m < MF; ++m) {                         \
      const float S = dx * W_reg[2 * m] + dy * W_reg[2 * m + 1];             \
      float sv, cv;                                                          \
      __sincosf(S, &sv, &cv);                                                \
      b += cv * beta_cos[m] + sv * beta_sin[m];                              \
    }                                                                        \
    bool mv;                                                                 \
    if (mflag == 1)      mv = ((const int*)mask_raw)[s] != 0;                \
    else if (mflag == 2) mv = ((const long long*)mask_raw)[s] != 0;          \
    else if (mflag == 3) mv = ((const float*)mask_raw)[s] != 0.f;            \
    else                 mv = ((const uint8_t*)mask_raw)[s] != 0;            \
    wout = mv ? fmaf(FB_COEF, b, 1.0f) : 0.f;                                \
  }
  CALC_EDGE(lane,      wa, sa)
  CALC_EDGE(lane + 64, wb, sb)
#undef CALC_EDGE

  // ---- preload region r0's W panel ----
  f4v cur[DEG_N], nxt[DEG_N];
  {
    const float* __restrict__ Wb0 =
        W_edges + (size_t)r0 * (DEG_N * D_DIM * D_DIM);
#pragma unroll
    for (int k = 0; k < DEG_N; ++k)
      cur[k] = __builtin_nontemporal_load(
          reinterpret_cast<const f4v*>(Wb0 + k * (D_DIM * D_DIM) + t * 4));
  }

#pragma unroll
  for (int it = 0; it < NR; ++it) {
    const int r = r0 + it * GRID;

    // edge params for this region: e = it*6+k is compile-time static, so
    // the wa/wb select and the shfl source lane are static too.
    float ww[DEG_N];
    int   ss[DEG_N];
#pragma unroll
    for (int k = 0; k < DEG_N; ++k) {
      const int e = it * DEG_N + k;
      ww[k] = __shfl(e < 64 ? wa : wb, e & 63);
      ss[k] = __shfl(e < 64 ? sa : sb, e & 63);
    }

    // 1) issue H loads for the current region (L2-resident, fast)
    float4 hv[DEG_N];
#pragma unroll
    for (int k = 0; k < DEG_N; ++k)
      hv[k] = *reinterpret_cast<const float4*>(&H[ss[k] * D_DIM + j0]);

    // 2) issue next region's 6 nontemporal W prefetches
    if (it + 1 < NR) {
      const float* __restrict__ Wn =
          W_edges + (size_t)(r + GRID) * (DEG_N * D_DIM * D_DIM);
#pragma unroll
      for (int k = 0; k < DEG_N; ++k)
        nxt[k] = __builtin_nontemporal_load(
            reinterpret_cast<const f4v*>(Wn + k * (D_DIM * D_DIM) + t * 4));
    }

    // 3) fma chain on current region (waits at vmcnt(6): prefetches fly on)
    float p = 0.f;
#pragma unroll
    for (int k = 0; k < DEG_N; ++k) {
      p = fmaf(ww[k],
               cur[k].x * hv[k].x + cur[k].y * hv[k].y +
               cur[k].z * hv[k].z + cur[k].w * hv[k].w,
               p);
    }

    // 4) reduce across the 16 lanes owning each output row
#pragma unroll
    for (int off = 1; off < 16; off <<= 1) p += __shfl_xor(p, off);
    const float p0 = __shfl(p, 0);
    const float p1 = __shfl(p, 16);
    const float p2 = __shfl(p, 32);
    const float p3 = __shfl(p, 48);
    if (lane == 0) {
      *reinterpret_cast<float4*>(&out[r * D_DIM + 4 * wid]) =
          make_float4(p0, p1, p2, p3);
    }

    // 5) rotate double buffer (all indices static under full unroll)
#pragma unroll
    for (int k = 0; k < DEG_N; ++k) cur[k] = nxt[k];
  }
}

extern "C" void kernel_launch(void* const* d_in, const int* in_sizes, int n_in,
                              void* d_out, int out_size, void* d_ws, size_t ws_size,
                              hipStream_t stream) {
  const float* H        = (const float*)d_in[0];
  const void*  mask     = d_in[1];
  const float* coords   = (const float*)d_in[2];
  const float* W_edges  = (const float*)d_in[3];
  const float* W_reg    = (const float*)d_in[4];
  const float* beta_cos = (const float*)d_in[5];
  const float* beta_sin = (const float*)d_in[6];
  const int*   src      = (const int*)d_in[7];
  // d_in[8] (dst) is structurally repeat(arange(R), 6); not needed.

  router_kernel<<<GRID, 1024, 0, stream>>>(H, mask, coords, W_edges, W_reg,
                                           beta_cos, beta_sin, src,
                                           (float*)d_out);
}

// Round 9
// 46.167 us; speedup vs baseline: 1.5732x; 1.4626x over previous
//
#include <hip/hip_runtime.h>
#include <stdint.h>

#define R_NUM 4096
#define D_DIM 64
#define DEG_N 6
#define MF 8
#define GRID 256                 // one persistent block per CU
#define NR (R_NUM / GRID)        // 16 regions per block
#define FB_COEF 0.035355339059327376f  // FB_ALPHA * FB_SCALE = 0.1/sqrt(8)

typedef float f4v __attribute__((ext_vector_type(4)));

// R9: mask-aware load skipping on top of the R8 persistent pipeline.
// w_edge = mask[src] * (1 + a*b); mask is Bernoulli(0.5) -> ~half the edges
// have w == 0 exactly, and their 16 KB W-matrix never needs to be fetched.
// ww[k] is wave-uniform (shfl broadcast), so `if (ww != 0)` is an exec-mask
// whole-wave skip: mandatory traffic drops ~403 -> ~203 MB.
// Output stores remain unconditional (harness poisons d_out with 0xAA).
__launch_bounds__(1024, 4)
__global__ void router_kernel(const float* __restrict__ H,
                              const void* __restrict__ mask_raw,
                              const float* __restrict__ coords,
                              const float* __restrict__ W_edges,
                              const float* __restrict__ W_reg,
                              const float* __restrict__ beta_cos,
                              const float* __restrict__ beta_sin,
                              const int* __restrict__ src,
                              float* __restrict__ out) {
  const int r0   = blockIdx.x;
  const int t    = threadIdx.x;
  const int lane = t & 63;
  const int wid  = t >> 6;          // wave id 0..15 -> output rows 4w..4w+3
  const int j0   = (t & 15) << 2;   // starting col of this lane's float4

  // ---- per-wave mask-dtype detection over the first 256 words (1 KB;
  // safe under every candidate encoding since the bool buffer is >= 4 KB).
  //  flag: 0 = 1-byte bool, 1 = int32, 2 = int64, 3 = float32
  const uint32_t* mw = (const uint32_t*)mask_raw;
  bool int01 = true, f01 = true, oddz = true, even1 = false;
#pragma unroll
  for (int i = 0; i < 4; ++i) {
    const int idx = lane + 64 * i;        // parity of idx == parity of lane
    const uint32_t v = mw[idx];
    int01 = int01 && (v <= 1u);
    f01   = f01 && (v == 0u || v == 0x3f800000u);
    if (lane & 1) oddz = oddz && (v == 0u);
    else          even1 = even1 || (v == 1u);
  }
  const bool all_int01 = (__ballot(int01) == ~0ULL);
  const bool all_f01   = (__ballot(f01)   == ~0ULL);
  const bool all_oddz  = (__ballot(!oddz) == 0ULL);
  const bool any_even1 = (__ballot(even1) != 0ULL);
  int mflag = 0;
  if (all_int01)    mflag = (all_oddz && any_even1) ? 2 : 1;
  else if (all_f01) mflag = 3;

  // ---- upfront edge weights: local edge ids 0..95; lane covers {lane,
  // lane+64}. li -> (it = li/6, k = li%6) -> region r0+it*GRID, edge k.
  float wa = 0.f, wb = 0.f;
  int   sa = 0,   sb = 0;
#define CALC_EDGE(li, wout, sout)                                            \
  if ((li) < DEG_N * NR) {                                                   \
    const int it = (li) / DEG_N;                                             \
    const int k  = (li) % DEG_N;                                             \
    const int rr = r0 + it * GRID;                                           \
    const int e  = rr * DEG_N + k;                                           \
    const int s  = src[e];                                                   \
    sout = s;                                                                \
    const float dx = coords[2 * rr]     - coords[2 * s];                     \
    const float dy = coords[2 * rr + 1] - coords[2 * s + 1];                 \
    float b = 0.f;                                                           \
    _Pragma("unroll") for (int m = 0; m < MF; ++m) {                         \
      const float S = dx * W_reg[2 * m] + dy * W_reg[2 * m + 1];             \
      float sv, cv;                                                          \
      __sincosf(S, &sv, &cv);                                                \
      b += cv * beta_cos[m] + sv * beta_sin[m];                              \
    }                                                                        \
    bool mv;                                                                 \
    if (mflag == 1)      mv = ((const int*)mask_raw)[s] != 0;                \
    else if (mflag == 2) mv = ((const long long*)mask_raw)[s] != 0;          \
    else if (mflag == 3) mv = ((const float*)mask_raw)[s] != 0.f;            \
    else                 mv = ((const uint8_t*)mask_raw)[s] != 0;            \
    wout = mv ? fmaf(FB_COEF, b, 1.0f) : 0.f;                                \
  }
  CALC_EDGE(lane,      wa, sa)
  CALC_EDGE(lane + 64, wb, sb)
#undef CALC_EDGE

  // e is compile-time static at every use site -> wa/wb select and shfl
  // source lane are static.
#define UNPACK(itc, wout, sout)                                              \
  _Pragma("unroll") for (int k = 0; k < DEG_N; ++k) {                        \
    const int e = (itc) * DEG_N + k;                                         \
    wout[k] = __shfl(e < 64 ? wa : wb, e & 63);                              \
    sout[k] = __shfl(e < 64 ? sa : sb, e & 63);                              \
  }

  const size_t PANEL = (size_t)DEG_N * D_DIM * D_DIM;

  // ---- preload region r0's W panel (active edges only) ----
  float cw[DEG_N]; int cs[DEG_N];
  UNPACK(0, cw, cs)
  f4v cur[DEG_N], nxt[DEG_N];
#pragma unroll
  for (int k = 0; k < DEG_N; ++k) { cur[k] = (f4v)(0.f); nxt[k] = (f4v)(0.f); }
  {
    const float* __restrict__ Wp = W_edges + (size_t)r0 * PANEL;
#pragma unroll
    for (int k = 0; k < DEG_N; ++k)
      if (cw[k] != 0.f)
        cur[k] = __builtin_nontemporal_load(
            reinterpret_cast<const f4v*>(Wp + k * (D_DIM * D_DIM) + t * 4));
  }

#pragma unroll
  for (int it = 0; it < NR; ++it) {
    const int r = r0 + it * GRID;

    // 1) issue next region's W prefetches (active edges only)
    float nw[DEG_N]; int ns[DEG_N];
#pragma unroll
    for (int k = 0; k < DEG_N; ++k) { nw[k] = 0.f; ns[k] = 0; }
    if (it + 1 < NR) {
      UNPACK(it + 1, nw, ns)
      const float* __restrict__ Wp = W_edges + (size_t)(r + GRID) * PANEL;
#pragma unroll
      for (int k = 0; k < DEG_N; ++k) {
        nxt[k] = (f4v)(0.f);
        if (nw[k] != 0.f)
          nxt[k] = __builtin_nontemporal_load(
              reinterpret_cast<const f4v*>(Wp + k * (D_DIM * D_DIM) + t * 4));
      }
    }

    // 2) fma chain on current region (skips are wave-uniform exec branches)
    float p = 0.f;
#pragma unroll
    for (int k = 0; k < DEG_N; ++k) {
      if (cw[k] != 0.f) {
        const float4 hv =
            *reinterpret_cast<const float4*>(&H[cs[k] * D_DIM + j0]);
        p = fmaf(cw[k],
                 cur[k].x * hv.x + cur[k].y * hv.y +
                 cur[k].z * hv.z + cur[k].w * hv.w,
                 p);
      }
    }

    // 3) reduce across the 16 lanes owning each output row
#pragma unroll
    for (int off = 1; off < 16; off <<= 1) p += __shfl_xor(p, off);
    const float p0 = __shfl(p, 0);
    const float p1 = __shfl(p, 16);
    const float p2 = __shfl(p, 32);
    const float p3 = __shfl(p, 48);
    if (lane == 0) {
      *reinterpret_cast<float4*>(&out[r * D_DIM + 4 * wid]) =
          make_float4(p0, p1, p2, p3);
    }

    // 4) rotate double buffer (all indices static under full unroll)
#pragma unroll
    for (int k = 0; k < DEG_N; ++k) {
      cur[k] = nxt[k]; cw[k] = nw[k]; cs[k] = ns[k];
    }
  }
#undef UNPACK
}

extern "C" void kernel_launch(void* const* d_in, const int* in_sizes, int n_in,
                              void* d_out, int out_size, void* d_ws, size_t ws_size,
                              hipStream_t stream) {
  const float* H        = (const float*)d_in[0];
  const void*  mask     = d_in[1];
  const float* coords   = (const float*)d_in[2];
  const float* W_edges  = (const float*)d_in[3];
  const float* W_reg    = (const float*)d_in[4];
  const float* beta_cos = (const float*)d_in[5];
  const float* beta_sin = (const float*)d_in[6];
  const int*   src      = (const int*)d_in[7];
  // d_in[8] (dst) is structurally repeat(arange(R), 6); not needed.

  router_kernel<<<GRID, 1024, 0, stream>>>(H, mask, coords, W_edges, W_reg,
                                           beta_cos, beta_sin, src,
                                           (float*)d_out);
}